// Round 8
// baseline (337.698 us; speedup 1.0000x reference)
//
#include <hip/hip_runtime.h>

// ---------------------------------------------------------------------------
// DelayGNN stage. CSR-gather (combined 2-hop edge list, src+hop*N encoding),
// bf16-MFMA GEMM with LDS-staged X/W (16-slot XOR swizzle), bf16 features.
//   xb = bf16(x); per layer t:
//     H1 = bf16((xb_t @ W1[t]) * (a0*invo1[row]))     mfma_f32_16x16x32_bf16
//     H2 = bf16((xb_{t-1} @ W2[t]) * (a1*invo2[row])) (t>0)
//     row r: agg = sum_{e in CSRc[r]} sc_e * Hcat[es_e]   sc = invi1|invi2
//     x_{t+1}[r] = l2norm(x_t[r] + relu(agg + bb[t]))   bb = a0*b1 + a1*b2
// ---------------------------------------------------------------------------

typedef unsigned short u16;
typedef __attribute__((ext_vector_type(8))) short short8;    // 8 bf16
typedef __attribute__((ext_vector_type(8))) unsigned short ushort8;
typedef __attribute__((ext_vector_type(4))) float f32x4;

__device__ inline float bf2f(u16 u) {
  return __uint_as_float(((unsigned int)u) << 16);
}
__device__ inline u16 f2bf(float f) {  // RNE
  unsigned int u = __float_as_uint(f);
  return (u16)((u + 0x7fff + ((u >> 16) & 1)) >> 16);
}

__global__ __launch_bounds__(64) void softmax_k(const float* __restrict__ alpha,
                                                float* __restrict__ a_soft, int Lnum) {
  int t = threadIdx.x;
  if (t >= Lnum) return;
  if (t == 0) { a_soft[0] = 1.0f; a_soft[1] = 0.0f; return; }
  float x0 = alpha[2 * t], x1 = alpha[2 * t + 1];
  float m = fmaxf(x0, x1);
  float e0 = expf(x0 - m), e1 = expf(x1 - m);
  float inv = 1.0f / (e0 + e1);
  a_soft[2 * t] = e0 * inv;
  a_soft[2 * t + 1] = e1 * inv;
}

__global__ __launch_bounds__(256) void prep_bb_k(const float* __restrict__ b1,
                                                 const float* __restrict__ b2,
                                                 const float* __restrict__ a_soft,
                                                 float* __restrict__ bb, int Lnum) {
  int id = blockIdx.x * 256 + threadIdx.x;
  if (id >= Lnum * 128) return;
  int t = id >> 7;
  bb[id] = a_soft[2 * t] * b1[id] + a_soft[2 * t + 1] * b2[id];
}

__global__ __launch_bounds__(256) void xcvt_k(const float* __restrict__ X,
                                              u16* __restrict__ Xb, size_t n8) {
  size_t id = (size_t)blockIdx.x * 256 + threadIdx.x;
  if (id >= n8) return;
  const float4* p = (const float4*)(X + id * 8);
  float4 v0 = p[0], v1 = p[1];
  ushort8 o;
  o[0] = f2bf(v0.x); o[1] = f2bf(v0.y); o[2] = f2bf(v0.z); o[3] = f2bf(v0.w);
  o[4] = f2bf(v1.x); o[5] = f2bf(v1.y); o[6] = f2bf(v1.z); o[7] = f2bf(v1.w);
  *(ushort8*)(Xb + id * 8) = o;
}

// W [k][n] fp32 -> Wt [n][k] bf16, all 2*Lnum matrices
__global__ __launch_bounds__(256) void prep_w_k(const float* __restrict__ W1,
                                                const float* __restrict__ W2,
                                                u16* __restrict__ Wt1,
                                                u16* __restrict__ Wt2, int Lnum) {
  int id = blockIdx.x * 256 + threadIdx.x;
  int per = 128 * 32;
  int mat = id / per, rem = id - mat * per;
  if (mat >= 2 * Lnum) return;
  int k = rem >> 5, n4 = (rem & 31) * 4;
  const float* W = (mat < Lnum) ? (W1 + (size_t)mat * 16384)
                                : (W2 + (size_t)(mat - Lnum) * 16384);
  u16* Wt = (mat < Lnum) ? (Wt1 + (size_t)mat * 16384)
                         : (Wt2 + (size_t)(mat - Lnum) * 16384);
  float4 v = *(const float4*)&W[k * 128 + n4];
  Wt[(size_t)(n4 + 0) * 128 + k] = f2bf(v.x);
  Wt[(size_t)(n4 + 1) * 128 + k] = f2bf(v.y);
  Wt[(size_t)(n4 + 2) * 128 + k] = f2bf(v.z);
  Wt[(size_t)(n4 + 3) * 128 + k] = f2bf(v.w);
}

// degree counts for both hops in one launch
__global__ __launch_bounds__(256) void deg_k(const int* __restrict__ src1,
                                             const int* __restrict__ dst1,
                                             const int* __restrict__ src2,
                                             const int* __restrict__ dst2,
                                             int* __restrict__ cnto1,
                                             int* __restrict__ cnti1,
                                             int* __restrict__ cnto2,
                                             int* __restrict__ cnti2,
                                             int E1, int E2) {
  int i = threadIdx.x + blockIdx.x * 256;
  if (i < E1) {
    atomicAdd(&cnto1[src1[i]], 1);
    atomicAdd(&cnti1[dst1[i]], 1);
  }
  int j = i - E1;
  if (j >= 0 && j < E2) {
    atomicAdd(&cnto2[src2[j]], 1);
    atomicAdd(&cnti2[dst2[j]], 1);
  }
}

__global__ __launch_bounds__(256) void inv_k(const int* __restrict__ cnt,
                                             float* __restrict__ inv, int n) {
  int i = threadIdx.x + blockIdx.x * 256;
  if (i >= n) return;
  int v = cnt[i];
  inv[i] = (v > 0) ? rsqrtf((float)v) : 0.0f;
}

__global__ __launch_bounds__(256) void addc_k(const int* __restrict__ a,
                                              const int* __restrict__ b,
                                              int* __restrict__ c, int n) {
  int i = threadIdx.x + blockIdx.x * 256;
  if (i < n) c[i] = a[i] + b[i];
}

__global__ __launch_bounds__(256) void psum_k(const int* __restrict__ cnt,
                                              int* __restrict__ bsums, int n) {
  int base = blockIdx.x * 1024 + threadIdx.x * 4;
  int s = 0;
#pragma unroll
  for (int j = 0; j < 4; ++j) { int i = base + j; if (i < n) s += cnt[i]; }
#pragma unroll
  for (int off = 1; off < 64; off <<= 1) s += __shfl_xor(s, off, 64);
  __shared__ int ws[4];
  int lane = threadIdx.x & 63, w = threadIdx.x >> 6;
  if (lane == 0) ws[w] = s;
  __syncthreads();
  if (threadIdx.x == 0) bsums[blockIdx.x] = ws[0] + ws[1] + ws[2] + ws[3];
}

__global__ __launch_bounds__(256) void bscan_k(const int* __restrict__ bsums,
                                               int* __restrict__ boffs,
                                               int* __restrict__ row_start,
                                               int nb, int n) {
  __shared__ int sm[256];
  int tid = threadIdx.x;
  int v = (tid < nb) ? bsums[tid] : 0;
  sm[tid] = v;
  __syncthreads();
  for (int off = 1; off < 256; off <<= 1) {
    int u = (tid >= off) ? sm[tid - off] : 0;
    __syncthreads();
    sm[tid] += u;
    __syncthreads();
  }
  if (tid < nb) boffs[tid] = sm[tid] - v;
  if (tid == 255) row_start[n] = sm[255];
}

__global__ __launch_bounds__(256) void sapply_k(const int* __restrict__ cnt,
                                                const int* __restrict__ boffs,
                                                int* __restrict__ row_start,
                                                int* __restrict__ cursor, int n) {
  int lane = threadIdx.x & 63, w = threadIdx.x >> 6;
  int base = blockIdx.x * 1024 + threadIdx.x * 4;
  int c[4], s = 0;
#pragma unroll
  for (int j = 0; j < 4; ++j) { int i = base + j; c[j] = (i < n) ? cnt[i] : 0; s += c[j]; }
  int incl = s;
#pragma unroll
  for (int off = 1; off < 64; off <<= 1) {
    int u = __shfl_up(incl, off, 64);
    if (lane >= off) incl += u;
  }
  int excl = incl - s;
  __shared__ int ws[4];
  if (lane == 63) ws[w] = incl;
  __syncthreads();
  int woff = 0;
  for (int i = 0; i < w; ++i) woff += ws[i];
  int off0 = boffs[blockIdx.x] + woff + excl;
#pragma unroll
  for (int j = 0; j < 4; ++j) {
    int i = base + j;
    if (i < n) { row_start[i] = off0; cursor[i] = off0; off0 += c[j]; }
  }
}

__global__ __launch_bounds__(256) void place_k(const int* __restrict__ src,
                                               const int* __restrict__ dst,
                                               int* __restrict__ cursor,
                                               int* __restrict__ esrc,
                                               int soff, int E) {
  int i = threadIdx.x + blockIdx.x * 256;
  if (i >= E) return;
  int slot = atomicAdd(&cursor[dst[i]], 1);
  esrc[slot] = src[i] + soff;
}

// H[r][c] = bf16((Xb[r][:] @ W[:,c]) * (a_soft[aidx]*invo[r])).
// X tile (16KB) + W (32KB) staged in LDS, both 16-slot XOR swizzled
// (col8 ^= (row&15)*8) -> conflict-free ds_read_b128 fragment reads.
// Block 256 = 4 waves x 16 rows; 8 col-frags x 4 k-steps of 16x16x32 MFMA.
__global__ __launch_bounds__(256) void gemm_mfma_k(
    const u16* __restrict__ Xb, const u16* __restrict__ Wt,
    u16* __restrict__ H, const float* __restrict__ invo,
    const float* __restrict__ a_soft, int aidx, int n) {
  __shared__ __align__(16) u16 wl[128 * 128];
  __shared__ __align__(16) u16 xl[64 * 128];
  int tid = threadIdx.x;
  int row0 = blockIdx.x * 64;
  bool tail = (row0 + 64 > n);
#pragma unroll
  for (int j = 0; j < 8; ++j) {            // stage W: 2048 x 16B
    int c = tid + 256 * j;
    int row = c >> 4, col8 = (c & 15) * 8;
    ushort8 v = *(const ushort8*)&Wt[(size_t)row * 128 + col8];
    *(ushort8*)&wl[row * 128 + (col8 ^ ((row & 15) * 8))] = v;
  }
#pragma unroll
  for (int j = 0; j < 4; ++j) {            // stage X tile: 1024 x 16B coalesced
    int c = tid + 256 * j;
    int r = c >> 4, col8 = (c & 15) * 8;
    int rr = row0 + r;
    ushort8 v = (ushort8){0, 0, 0, 0, 0, 0, 0, 0};
    if (!tail || rr < n) v = *(const ushort8*)&Xb[(size_t)rr * 128 + col8];
    *(ushort8*)&xl[r * 128 + (col8 ^ ((r & 15) * 8))] = v;
  }
  __syncthreads();

  int lane = tid & 63, w = tid >> 6;
  int m15 = lane & 15, kg = lane >> 4;
  int ar = w * 16 + m15;

  f32x4 acc[8];
#pragma unroll
  for (int i = 0; i < 8; ++i) acc[i] = (f32x4){0.f, 0.f, 0.f, 0.f};

#pragma unroll
  for (int ks = 0; ks < 4; ++ks) {
    int acol = (kg * 8 + ks * 32) ^ ((ar & 15) * 8);
    short8 a = *(const short8*)&xl[ar * 128 + acol];
#pragma unroll
    for (int fn = 0; fn < 8; ++fn) {
      int brow = fn * 16 + m15;
      int bcol = (kg * 8 + ks * 32) ^ ((brow & 15) * 8);
      short8 b = *(const short8*)&wl[brow * 128 + bcol];
      acc[fn] = __builtin_amdgcn_mfma_f32_16x16x32_bf16(a, b, acc[fn], 0, 0, 0);
    }
  }

  float as = a_soft[aidx];
  int rbase = row0 + w * 16 + kg * 4;
  if (!tail) {
    float4 iv = *(const float4*)&invo[rbase];
    float scv[4] = {as * iv.x, as * iv.y, as * iv.z, as * iv.w};
    u16* hb = &H[(size_t)rbase * 128 + m15];
#pragma unroll
    for (int fn = 0; fn < 8; ++fn)
#pragma unroll
      for (int r = 0; r < 4; ++r)
        hb[r * 128 + fn * 16] = f2bf(acc[fn][r] * scv[r]);
  } else {
    float scv[4];
#pragma unroll
    for (int r = 0; r < 4; ++r)
      scv[r] = (rbase + r < n) ? as * invo[rbase + r] : 0.f;
#pragma unroll
    for (int fn = 0; fn < 8; ++fn)
#pragma unroll
      for (int r = 0; r < 4; ++r) {
        int rr = rbase + r;
        if (rr < n) H[(size_t)rr * 128 + fn * 16 + m15] = f2bf(acc[fn][r] * scv[r]);
      }
  }
}

// unpack 8 bf16 and fma-accumulate with per-edge scale into 4 float2
__device__ inline void fma_acc(float2* a, uint4 h, float sc) {
  a[0].x += sc * __uint_as_float(h.x << 16);
  a[0].y += sc * __uint_as_float(h.x & 0xffff0000u);
  a[1].x += sc * __uint_as_float(h.y << 16);
  a[1].y += sc * __uint_as_float(h.y & 0xffff0000u);
  a[2].x += sc * __uint_as_float(h.z << 16);
  a[2].y += sc * __uint_as_float(h.z & 0xffff0000u);
  a[3].x += sc * __uint_as_float(h.w << 16);
  a[3].y += sc * __uint_as_float(h.w & 0xffff0000u);
}

// fused gather + bias + relu + residual + l2norm; one wave per row.
// Combined CSR: es[e] = src + hop*N, gather from contiguous H = h1|h2;
// per-edge scale selects invi1/invi2. 16-lane groups x4 edges in flight,
// edge loop unrolled x2.
__global__ __launch_bounds__(256) void aggfin_k(
    const u16* __restrict__ Xb, const u16* __restrict__ H,
    const int* __restrict__ rs, const int* __restrict__ es,
    const float* __restrict__ invi1, const float* __restrict__ invi2,
    const float* __restrict__ bb,
    u16* __restrict__ XnB, float* __restrict__ XnF,
    int n, int final_f32) {
  int w = threadIdx.x >> 6, lane = threadIdx.x & 63;
  int row = blockIdx.x * 4 + w;
  if (row >= n) return;
  int grp = lane >> 4, l16 = lane & 15;
  int c8 = l16 * 8;

  float gi1 = invi1[row], gi2 = invi2[row];
  float2 a[4] = {{0.f, 0.f}, {0.f, 0.f}, {0.f, 0.f}, {0.f, 0.f}};
  int e = rs[row] + grp, e1 = rs[row + 1];
  while (e + 4 < e1) {
    int s0 = es[e], s1 = es[e + 4];
    float sc0 = (s0 >= n) ? gi2 : gi1;
    float sc1 = (s1 >= n) ? gi2 : gi1;
    uint4 h0 = *(const uint4*)&H[(size_t)s0 * 128 + c8];
    uint4 h1 = *(const uint4*)&H[(size_t)s1 * 128 + c8];
    fma_acc(a, h0, sc0);
    fma_acc(a, h1, sc1);
    e += 8;
  }
  if (e < e1) {
    int s = es[e];
    float sc = (s >= n) ? gi2 : gi1;
    uint4 h = *(const uint4*)&H[(size_t)s * 128 + c8];
    fma_acc(a, h, sc);
  }

  float t[8] = {a[0].x, a[0].y, a[1].x, a[1].y, a[2].x, a[2].y, a[3].x, a[3].y};
#pragma unroll
  for (int j = 0; j < 8; ++j) t[j] += __shfl_xor(t[j], 16, 64);
#pragma unroll
  for (int j = 0; j < 8; ++j) t[j] += __shfl_xor(t[j], 32, 64);

  float4 bv0 = *(const float4*)&bb[c8];
  float4 bv1 = *(const float4*)&bb[c8 + 4];
  float bbv[8] = {bv0.x, bv0.y, bv0.z, bv0.w, bv1.x, bv1.y, bv1.z, bv1.w};
  ushort8 xv = *(const ushort8*)&Xb[(size_t)row * 128 + c8];
  float v[8];
  float ss = 0.f;
#pragma unroll
  for (int j = 0; j < 8; ++j) {
    v[j] = bf2f(xv[j]) + fmaxf(t[j] + bbv[j], 0.f);
    ss += v[j] * v[j];
  }
#pragma unroll
  for (int off = 1; off <= 8; off <<= 1) ss += __shfl_xor(ss, off, 64);
  float inv = 1.0f / fmaxf(sqrtf(ss), 1e-12f);

  if (final_f32) {
    if (grp == 0) {
      float4 o0 = make_float4(v[0] * inv, v[1] * inv, v[2] * inv, v[3] * inv);
      float4 o1 = make_float4(v[4] * inv, v[5] * inv, v[6] * inv, v[7] * inv);
      *(float4*)&XnF[(size_t)row * 128 + c8] = o0;
      *(float4*)&XnF[(size_t)row * 128 + c8 + 4] = o1;
    }
  } else {
    if (grp == 0) {
      ushort8 o;
#pragma unroll
      for (int j = 0; j < 8; ++j) o[j] = f2bf(v[j] * inv);
      *(ushort8*)&XnB[(size_t)row * 128 + c8] = o;
    }
  }
}

extern "C" void kernel_launch(void* const* d_in, const int* in_sizes, int n_in,
                              void* d_out, int out_size, void* d_ws, size_t ws_size,
                              hipStream_t stream) {
  const float* x_in  = (const float*)d_in[0];
  const float* W1    = (const float*)d_in[1];
  const float* b1    = (const float*)d_in[2];
  const float* W2    = (const float*)d_in[3];
  const float* b2    = (const float*)d_in[4];
  const float* alpha = (const float*)d_in[5];
  const int* src1 = (const int*)d_in[6];
  const int* dst1 = (const int*)d_in[7];
  const int* src2 = (const int*)d_in[8];
  const int* dst2 = (const int*)d_in[9];

  int N = in_sizes[0] / 128;
  int Lnum = in_sizes[5] / 2;
  int E1 = in_sizes[6], E2 = in_sizes[8];

  size_t ND = (size_t)N * 128;
  u16* xb0 = (u16*)d_ws;             // 3 bf16 x buffers (x3 reuses xb0)
  u16* xbA = xb0 + ND;
  u16* xbB = xbA + ND;
  u16* h1  = xbB + ND;               // h1|h2 contiguous (combined gather)
  u16* h2  = h1 + ND;
  float* degs = (float*)(h2 + ND);   // 4*N floats: invo1, invi1, invo2, invi2
  float* a_soft = degs + 4 * (size_t)N;
  float* bb = a_soft + 64;           // Lnum*128
  int* ibase = (int*)(bb + 512);
  int* cnto1 = ibase;                // order must match degs: o1,i1,o2,i2
  int* cnti1 = cnto1 + N;
  int* cnto2 = cnti1 + N;
  int* cnti2 = cnto2 + N;
  int* cntc  = cnti2 + N;            // N  combined in-degree
  int* rs1   = cntc + N;             // N+1
  int* rsc   = rs1 + N + 1;          // N+1
  int* cur1  = rsc + N + 1;          // N
  int* curc  = cur1 + N;             // N
  int* bsum  = curc + N;             // 256
  int* boff  = bsum + 256;           // 256
  int* es1   = boff + 256;           // E1
  int* esc   = es1 + E1;             // E1+E2
  u16* wt1 = (u16*)((((uintptr_t)(esc + E1 + E2)) + 15) & ~(uintptr_t)15);
  u16* wt2 = wt1 + (size_t)Lnum * 16384;

  float* invo1 = degs;
  float* invi1 = degs + N;
  float* invo2 = degs + 2 * (size_t)N;
  float* invi2 = degs + 3 * (size_t)N;

  int nb = (N + 1023) / 1024;

  hipMemsetAsync(cnto1, 0, 4 * (size_t)N * sizeof(int), stream);
  softmax_k<<<1, 64, 0, stream>>>(alpha, a_soft, Lnum);
  prep_bb_k<<<(Lnum * 128 + 255) / 256, 256, 0, stream>>>(b1, b2, a_soft, bb, Lnum);
  prep_w_k<<<(2 * Lnum * 4096 + 255) / 256, 256, 0, stream>>>(W1, W2, wt1, wt2, Lnum);
  xcvt_k<<<(int)((ND / 8 + 255) / 256), 256, 0, stream>>>(x_in, xb0, ND / 8);
  deg_k<<<(E1 + E2 + 255) / 256, 256, 0, stream>>>(src1, dst1, src2, dst2,
                                                   cnto1, cnti1, cnto2, cnti2, E1, E2);
  inv_k<<<(4 * N + 255) / 256, 256, 0, stream>>>(cnto1, degs, 4 * N);
  addc_k<<<(N + 255) / 256, 256, 0, stream>>>(cnti1, cnti2, cntc, N);
  // CSR hop1 (t=0)
  psum_k<<<nb, 256, 0, stream>>>(cnti1, bsum, N);
  bscan_k<<<1, 256, 0, stream>>>(bsum, boff, rs1, nb, N);
  sapply_k<<<nb, 256, 0, stream>>>(cnti1, boff, rs1, cur1, N);
  // combined CSR (t>0)
  psum_k<<<nb, 256, 0, stream>>>(cntc, bsum, N);
  bscan_k<<<1, 256, 0, stream>>>(bsum, boff, rsc, nb, N);
  sapply_k<<<nb, 256, 0, stream>>>(cntc, boff, rsc, curc, N);
  place_k<<<(E1 + 255) / 256, 256, 0, stream>>>(src1, dst1, cur1, es1, 0, E1);
  place_k<<<(E1 + 255) / 256, 256, 0, stream>>>(src1, dst1, curc, esc, 0, E1);
  place_k<<<(E2 + 255) / 256, 256, 0, stream>>>(src2, dst2, curc, esc, N, E2);

  float* out = (float*)d_out;
  int gemm_grid = (N + 63) / 64;
  int fin_grid = (N + 3) / 4;

  // x buffers per layer: x0=xb0, x1=xbA, x2=xbB, x3=xb0 (x0 dead after t=1)
  u16* xbuf[8];
  xbuf[0] = xb0; xbuf[1] = xbA; xbuf[2] = xbB;
  for (int i = 3; i < 8; ++i) xbuf[i] = xbuf[i - 3];

  for (int t = 0; t < Lnum; ++t) {
    const u16* cur = xbuf[t];
    const u16* prev = (t > 0) ? xbuf[t - 1] : nullptr;
    int fin = (t == Lnum - 1);
    u16* nxt = fin ? nullptr : xbuf[t + 1];
    gemm_mfma_k<<<gemm_grid, 256, 0, stream>>>(cur, wt1 + (size_t)t * 16384, h1,
                                               invo1, a_soft, 2 * t, N);
    if (t > 0)
      gemm_mfma_k<<<gemm_grid, 256, 0, stream>>>(prev, wt2 + (size_t)t * 16384, h2,
                                                 invo2, a_soft, 2 * t + 1, N);
    aggfin_k<<<fin_grid, 256, 0, stream>>>(cur, h1,
                                           (t == 0) ? rs1 : rsc,
                                           (t == 0) ? es1 : esc,
                                           invi1, invi2, bb + (size_t)t * 128,
                                           nxt, out, N, fin);
  }
}